// Round 1
// baseline (449.462 us; speedup 1.0000x reference)
//
#include <hip/hip_runtime.h>

#define B_ 4
#define S_ 4096
#define T_ 4096
#define NH_ 16
#define NCHUNK 8
#define CHUNK 512  // S_/NCHUNK

// ---------------- Kernel A: per-(b,t) top-16 smallest distances ----------------
// Grid: B_*T_/64 = 256 blocks x 512 threads.
// Thread (ic, itl): chunk ic of column t = tblk*64+itl. Lanes = consecutive t -> coalesced.
__global__ __launch_bounds__(512) void topk_kernel(
    const float* __restrict__ coords,   // [2][B][S][T]
    float* __restrict__ outW,           // [B][T][NH]  w = 1/(sqrt(d2)+1e-15)^2
    int*   __restrict__ outI)           // [B][T][NH]
{
    __shared__ float          lv[NCHUNK][64][NH_ + 1];  // +1 pad: merge-read bank spread
    __shared__ unsigned short li[NCHUNK][64][NH_ + 1];

    const int blk  = blockIdx.x;        // [0, 256)
    const int ib   = blk >> 6;          // blk / (T_/64)
    const int tblk = blk & 63;
    const int itl  = threadIdx.x & 63;
    const int ic   = threadIdx.x >> 6;
    const int t    = tblk * 64 + itl;

    const size_t plane = (size_t)B_ * S_ * T_;
    const float* q0 = coords + (size_t)ib * S_ * T_ + (size_t)(ic * CHUNK) * T_ + t;
    const float* q1 = q0 + plane;

    float vals[NH_];
    int   idxs[NH_];
#pragma unroll
    for (int j = 0; j < NH_; ++j) { vals[j] = __int_as_float(0x7f800000); idxs[j] = 0; }

    const int s0 = ic * CHUNK;
    for (int ss = 0; ss < CHUNK; ss += 8) {
        float dx[8], dy[8];
#pragma unroll
        for (int u = 0; u < 8; ++u) {
            dx[u] = q0[(size_t)(ss + u) * T_];
            dy[u] = q1[(size_t)(ss + u) * T_];
        }
#pragma unroll
        for (int u = 0; u < 8; ++u) {
            float d2 = dx[u] * dx[u] + dy[u] * dy[u];
            if (d2 < vals[NH_ - 1]) {           // guard: skip when whole wave rejects
                float v = d2; int vi = s0 + ss + u;
#pragma unroll
                for (int j = 0; j < NH_; ++j) { // sorted insert via compare-swap chain
                    bool sw = v < vals[j];
                    float tv = vals[j]; int ti = idxs[j];
                    vals[j] = sw ? v : tv;  idxs[j] = sw ? vi : ti;
                    v = sw ? tv : v;        vi = sw ? ti : vi;
                }
            }
        }
    }

#pragma unroll
    for (int j = 0; j < NH_; ++j) {
        lv[ic][itl][j] = vals[j];
        li[ic][itl][j] = (unsigned short)idxs[j];
    }
    __syncthreads();

    // merge 8 ascending 16-lists per column; wave 0 handles the block's 64 columns
    if (threadIdx.x < 64) {
        float cv[NH_]; int ci[NH_];
#pragma unroll
        for (int j = 0; j < NH_; ++j) { cv[j] = __int_as_float(0x7f800000); ci[j] = 0; }
        for (int c = 0; c < NCHUNK; ++c) {
            for (int j = 0; j < NH_; ++j) {
                float v = lv[c][itl][j];
                if (!(v < cv[NH_ - 1])) break;  // ascending list: rest can't qualify
                int vi = (int)li[c][itl][j];
#pragma unroll
                for (int k = 0; k < NH_; ++k) {
                    bool sw = v < cv[k];
                    float tv = cv[k]; int ti = ci[k];
                    cv[k] = sw ? v : tv;  ci[k] = sw ? vi : ti;
                    v = sw ? tv : v;      vi = sw ? ti : vi;
                }
            }
        }
        const size_t base = ((size_t)ib * T_ + t) * NH_;
#pragma unroll
        for (int j = 0; j < NH_; ++j) {
            float d = sqrtf(cv[j]) + 1e-15f;    // match reference: sqrt then +eps, ^2, recip
            outW[base + j] = 1.0f / (d * d);
            outI[base + j] = ci[j];
        }
    }
}

// ---------------- Kernel B: denom[b][nh] = sum_t w ----------------
__global__ __launch_bounds__(256) void denom_kernel(
    const float* __restrict__ outW, float* __restrict__ denom)
{
    const int ib = blockIdx.x >> 4;
    const int ih = blockIdx.x & 15;
    __shared__ float red[256];
    float acc = 0.f;
    for (int it = threadIdx.x; it < T_; it += 256)
        acc += outW[((size_t)ib * T_ + it) * NH_ + ih];
    red[threadIdx.x] = acc;
    __syncthreads();
    for (int s = 128; s > 0; s >>= 1) {
        if (threadIdx.x < s) red[threadIdx.x] += red[threadIdx.x + s];
        __syncthreads();
    }
    if (threadIdx.x == 0) denom[blockIdx.x] = red[0];
}

// ---------------- Kernel C: final gather + weighted sum ----------------
// out[i,j] = sum_k x[i, IDX[i][ih][it]] * W[i][ih][it] / denom[j%4][k]
//   with ih = j>>8 (constant per thread), it = (j&255)*16 + k
__global__ __launch_bounds__(256) void out_kernel(
    const float* __restrict__ x,        // [B][S]
    const float* __restrict__ outW,     // [B][T][NH]
    const int*   __restrict__ outI,
    const float* __restrict__ denom,    // [B][NH]
    float* __restrict__ out)            // [B][T]
{
    const int gid = blockIdx.x * 256 + threadIdx.x;   // [0, B_*T_)
    const int i = gid >> 12;
    const int j = gid & 4095;
    const int ih = j >> 8;
    const size_t base = ((size_t)i * T_ + (size_t)(j & 255) * NH_) * NH_ + ih;
    const int dq = (j & 3) * NH_;
    float acc = 0.f;
#pragma unroll
    for (int k = 0; k < NH_; ++k) {
        float w  = outW[base + (size_t)k * NH_];
        int   id = outI[base + (size_t)k * NH_];
        acc += x[i * S_ + id] * w / denom[dq + k];
    }
    out[gid] = acc;
}

extern "C" void kernel_launch(void* const* d_in, const int* in_sizes, int n_in,
                              void* d_out, int out_size, void* d_ws, size_t ws_size,
                              hipStream_t stream) {
    const float* x      = (const float*)d_in[0];
    const float* coords = (const float*)d_in[1];
    float* out = (float*)d_out;

    float* outW  = (float*)d_ws;                              // 262144 f32
    int*   outI  = (int*)(outW + (size_t)B_ * T_ * NH_);      // 262144 i32
    float* denom = (float*)(outI + (size_t)B_ * T_ * NH_);    // 64 f32

    topk_kernel <<<B_ * T_ / 64, 512, 0, stream>>>(coords, outW, outI);
    denom_kernel<<<B_ * NH_,     256, 0, stream>>>(outW, denom);
    out_kernel  <<<B_ * T_ / 256,256, 0, stream>>>(x, outW, outI, denom, out);
}

// Round 2
// 365.706 us; speedup vs baseline: 1.2290x; 1.2290x over previous
//
#include <hip/hip_runtime.h>

#define B_ 4
#define S_ 4096
#define T_ 4096
#define NH_ 16
#define SLICE 128          // s-elements per wave
#define NSB 8              // s-spans per column (each block covers 4 slices = 512 s)

// ---------------- Kernel A: sliced top-16 scan ----------------
// grid = B*(T/64)*NSB = 2048 blocks x 256 threads (4 waves).
// Wave ic owns 64 consecutive t-columns x s-slice [s0, s0+SLICE).
__global__ __launch_bounds__(256) void topk_scan(
    const float* __restrict__ coords,   // [2][B][S][T]
    float* __restrict__ pv,             // [2048][NH][64] partial vals (d^2, ascending)
    unsigned short* __restrict__ pi)    // [2048][NH][64] partial idx
{
    __shared__ float          lv[4][64][NH_ + 1];
    __shared__ unsigned short li[4][64][NH_ + 1];

    const int bid = blockIdx.x;
    const int cg  = bid >> 3;           // column group = ib*64 + tg
    const int sb  = bid & 7;
    const int ib  = cg >> 6;
    const int tg  = cg & 63;
    const int itl = threadIdx.x & 63;
    const int ic  = threadIdx.x >> 6;
    const int t   = tg * 64 + itl;
    const int s0  = sb * (4 * SLICE) + ic * SLICE;

    const size_t plane = (size_t)B_ * S_ * T_;
    const float* q0 = coords + (size_t)ib * S_ * T_ + (size_t)s0 * T_ + t;
    const float* q1 = q0 + plane;

    float vals[NH_];
    int   idxs[NH_];
#pragma unroll
    for (int j = 0; j < NH_; ++j) { vals[j] = __int_as_float(0x7f800000); idxs[j] = 0; }

    for (int ss = 0; ss < SLICE; ss += 8) {
        float dx[8], dy[8];
#pragma unroll
        for (int u = 0; u < 8; ++u) {
            dx[u] = q0[(size_t)(ss + u) * T_];
            dy[u] = q1[(size_t)(ss + u) * T_];
        }
#pragma unroll
        for (int u = 0; u < 8; ++u) {
            float d2 = dx[u] * dx[u] + dy[u] * dy[u];
            if (d2 < vals[NH_ - 1]) {
                float v = d2; int vi = s0 + ss + u;
#pragma unroll
                for (int j = 0; j < NH_; ++j) {
                    bool sw = v < vals[j];
                    float tv = vals[j]; int ti = idxs[j];
                    vals[j] = sw ? v : tv;  idxs[j] = sw ? vi : ti;
                    v = sw ? tv : v;        vi = sw ? ti : vi;
                }
            }
        }
    }

#pragma unroll
    for (int j = 0; j < NH_; ++j) {
        lv[ic][itl][j] = vals[j];
        li[ic][itl][j] = (unsigned short)idxs[j];
    }
    __syncthreads();

    // wave 0: merge the block's 4 ascending lists per column, write partial list
    if (threadIdx.x < 64) {
        float cv[NH_]; int ci[NH_];
#pragma unroll
        for (int j = 0; j < NH_; ++j) { cv[j] = __int_as_float(0x7f800000); ci[j] = 0; }
        for (int c = 0; c < 4; ++c) {
            for (int j = 0; j < NH_; ++j) {
                float v = lv[c][itl][j];
                if (!(v < cv[NH_ - 1])) break;
                int vi = (int)li[c][itl][j];
#pragma unroll
                for (int k = 0; k < NH_; ++k) {
                    bool sw = v < cv[k];
                    float tv = cv[k]; int ti = ci[k];
                    cv[k] = sw ? v : tv;  ci[k] = sw ? vi : ti;
                    v = sw ? tv : v;      vi = sw ? ti : vi;
                }
            }
        }
        // layout [bid][j][64]: coalesced 256B stores per j
#pragma unroll
        for (int j = 0; j < NH_; ++j) {
            pv[((size_t)bid * NH_ + j) * 64 + itl] = cv[j];
            pi[((size_t)bid * NH_ + j) * 64 + itl] = (unsigned short)ci[j];
        }
    }
}

// ---------------- Kernel B: merge 8 partial lists per column ----------------
// one thread per column; lanes = 64 consecutive columns of the same cg -> coalesced
__global__ __launch_bounds__(256) void topk_merge(
    const float* __restrict__ pv, const unsigned short* __restrict__ pi,
    float* __restrict__ outW,           // [B][T][NH]
    int*   __restrict__ outI)
{
    const int c   = blockIdx.x * 256 + threadIdx.x;  // [0, B*T)
    const int cg  = c >> 6;
    const int itl = c & 63;

    float cv[NH_]; int ci[NH_];
#pragma unroll
    for (int j = 0; j < NH_; ++j) { cv[j] = __int_as_float(0x7f800000); ci[j] = 0; }

    for (int sb = 0; sb < NSB; ++sb) {
        const size_t base = ((size_t)(cg * NSB + sb) * NH_) * 64 + itl;
        for (int j = 0; j < NH_; ++j) {
            float v = pv[base + (size_t)j * 64];
            if (!(v < cv[NH_ - 1])) break;       // slices processed in ascending s: stable ties
            int vi = (int)pi[base + (size_t)j * 64];
#pragma unroll
            for (int k = 0; k < NH_; ++k) {
                bool sw = v < cv[k];
                float tv = cv[k]; int ti = ci[k];
                cv[k] = sw ? v : tv;  ci[k] = sw ? vi : ti;
                v = sw ? tv : v;      vi = sw ? ti : vi;
            }
        }
    }

    const size_t base = (size_t)c * NH_;
#pragma unroll
    for (int j = 0; j < NH_; ++j) {
        float d = sqrtf(cv[j]) + 1e-15f;
        outW[base + j] = 1.0f / (d * d);
        outI[base + j] = ci[j];
    }
}

// ---------------- Kernel C: denom[b][nh] = sum_t w ----------------
__global__ __launch_bounds__(256) void denom_kernel(
    const float* __restrict__ outW, float* __restrict__ denom)
{
    const int ib = blockIdx.x >> 4;
    const int ih = blockIdx.x & 15;
    __shared__ float red[256];
    float acc = 0.f;
    for (int it = threadIdx.x; it < T_; it += 256)
        acc += outW[((size_t)ib * T_ + it) * NH_ + ih];
    red[threadIdx.x] = acc;
    __syncthreads();
    for (int s = 128; s > 0; s >>= 1) {
        if (threadIdx.x < s) red[threadIdx.x] += red[threadIdx.x + s];
        __syncthreads();
    }
    if (threadIdx.x == 0) denom[blockIdx.x] = red[0];
}

// ---------------- Kernel D: final gather + weighted sum ----------------
__global__ __launch_bounds__(256) void out_kernel(
    const float* __restrict__ x,        // [B][S]
    const float* __restrict__ outW,
    const int*   __restrict__ outI,
    const float* __restrict__ denom,    // [B][NH]
    float* __restrict__ out)            // [B][T]
{
    const int gid = blockIdx.x * 256 + threadIdx.x;
    const int i = gid >> 12;
    const int j = gid & 4095;
    const int ih = j >> 8;
    const size_t base = ((size_t)i * T_ + (size_t)(j & 255) * NH_) * NH_ + ih;
    const int dq = (j & 3) * NH_;
    float acc = 0.f;
#pragma unroll
    for (int k = 0; k < NH_; ++k) {
        float w  = outW[base + (size_t)k * NH_];
        int   id = outI[base + (size_t)k * NH_];
        acc += x[i * S_ + id] * w / denom[dq + k];
    }
    out[gid] = acc;
}

extern "C" void kernel_launch(void* const* d_in, const int* in_sizes, int n_in,
                              void* d_out, int out_size, void* d_ws, size_t ws_size,
                              hipStream_t stream) {
    const float* x      = (const float*)d_in[0];
    const float* coords = (const float*)d_in[1];
    float* out = (float*)d_out;

    const int nblocks = B_ * (T_ / 64) * NSB;                 // 2048
    float*          pv    = (float*)d_ws;                     // 2048*16*64 f32 = 8 MB
    unsigned short* pi    = (unsigned short*)(pv + (size_t)nblocks * NH_ * 64);  // 4 MB
    float*          outW  = (float*)(pi + (size_t)nblocks * NH_ * 64);           // 1 MB
    int*            outI  = (int*)(outW + (size_t)B_ * T_ * NH_);                // 1 MB
    float*          denom = (float*)(outI + (size_t)B_ * T_ * NH_);              // 64 f32

    topk_scan   <<<nblocks,        256, 0, stream>>>(coords, pv, pi);
    topk_merge  <<<B_ * T_ / 256,  256, 0, stream>>>(pv, pi, outW, outI);
    denom_kernel<<<B_ * NH_,       256, 0, stream>>>(outW, denom);
    out_kernel  <<<B_ * T_ / 256,  256, 0, stream>>>(x, outW, outI, denom, out);
}

// Round 3
// 223.902 us; speedup vs baseline: 2.0074x; 1.6333x over previous
//
#include <hip/hip_runtime.h>

#define B_ 4
#define S_ 4096
#define T_ 4096
#define NH_ 16
#define SLICE 256          // s-elements per wave-slice
#define NSB 16             // slices per column (4096/256)

typedef unsigned long long u64;

__device__ __forceinline__ void ce(u64 &x, u64 &y) {   // after: x=min, y=max
    bool c = x < y;
    u64 t = x;
    x = c ? x : y;
    y = c ? y : t;
}
__device__ __forceinline__ void cemin(u64 &x, u64 y) { // x = min(x,y)
    x = x < y ? x : y;
}

// ---------------- Kernel A: sliced top-16 scan, bitonic batch updates ----------------
// grid = B*(T/64)*NSB/4 = 1024 blocks x 256 threads (4 waves, each one slice).
// Wave owns 64 consecutive t-columns x s-slice [s0, s0+SLICE). No LDS, no sync.
__global__ __launch_bounds__(256, 4) void topk_scan(
    const float* __restrict__ coords,   // [2][B][S][T]
    float* __restrict__ pv,             // [4096 waves][NH][64] partial d2, ascending
    unsigned short* __restrict__ pi)    // [4096 waves][NH][64] partial idx
{
    const int bid = blockIdx.x;
    const int cg  = bid >> 2;                 // column group [0,256)
    const int ic  = threadIdx.x >> 6;
    const int sb  = (bid & 3) * 4 + ic;       // slice [0,16)
    const int itl = threadIdx.x & 63;
    const int ib  = cg >> 6;
    const int tg  = cg & 63;
    const int t   = tg * 64 + itl;
    const int s0  = sb * SLICE;

    const size_t plane = (size_t)B_ * S_ * T_;
    const float* q0 = coords + (size_t)ib * S_ * T_ + (size_t)s0 * T_ + t;
    const float* q1 = q0 + plane;

    u64 l[16];
#pragma unroll
    for (int j = 0; j < 16; ++j) l[j] = ((u64)0x7f800000u << 32);

#pragma unroll 1
    for (int ss = 0; ss < SLICE; ss += 8) {
        float dx[8], dy[8];
#pragma unroll
        for (int u = 0; u < 8; ++u) {
            dx[u] = q0[(size_t)(ss + u) * T_];
            dy[u] = q1[(size_t)(ss + u) * T_];
        }
        u64 a[8];
#pragma unroll
        for (int u = 0; u < 8; ++u) {
            float d2 = dx[u] * dx[u] + dy[u] * dy[u];
            a[u] = ((u64)__float_as_uint(d2) << 32) | (unsigned)(s0 + ss + u);
        }
        // ---- sort8 ascending: sort4 + sort4 + Batcher odd-even merge (19 CE) ----
        ce(a[0],a[1]); ce(a[2],a[3]); ce(a[0],a[2]); ce(a[1],a[3]); ce(a[1],a[2]);
        ce(a[4],a[5]); ce(a[6],a[7]); ce(a[4],a[6]); ce(a[5],a[7]); ce(a[5],a[6]);
        ce(a[0],a[4]); ce(a[1],a[5]); ce(a[2],a[6]); ce(a[3],a[7]);
        ce(a[2],a[4]); ce(a[3],a[5]);
        ce(a[1],a[2]); ce(a[3],a[4]); ce(a[5],a[6]);
        // ---- select: lower half of bitonic split of (l asc ++ rev(a++inf)) ----
#pragma unroll
        for (int j = 0; j < 8; ++j) cemin(l[8 + j], a[7 - j]);
        // ---- bitonic merge 16 (l is bitonic) ----
#pragma unroll
        for (int i = 0; i < 8; ++i) ce(l[i], l[i + 8]);
        ce(l[0],l[4]); ce(l[1],l[5]); ce(l[2],l[6]); ce(l[3],l[7]);
        ce(l[8],l[12]); ce(l[9],l[13]); ce(l[10],l[14]); ce(l[11],l[15]);
        ce(l[0],l[2]); ce(l[1],l[3]); ce(l[4],l[6]); ce(l[5],l[7]);
        ce(l[8],l[10]); ce(l[9],l[11]); ce(l[12],l[14]); ce(l[13],l[15]);
        ce(l[0],l[1]); ce(l[2],l[3]); ce(l[4],l[5]); ce(l[6],l[7]);
        ce(l[8],l[9]); ce(l[10],l[11]); ce(l[12],l[13]); ce(l[14],l[15]);
    }

    // store partial list: wave id w = cg*16+sb; layout [w][j][64] -> coalesced
    const int w = cg * NSB + sb;
#pragma unroll
    for (int j = 0; j < 16; ++j) {
        pv[((size_t)w * NH_ + j) * 64 + itl] = __uint_as_float((unsigned)(l[j] >> 32));
        pi[((size_t)w * NH_ + j) * 64 + itl] = (unsigned short)(l[j] & 0xFFFFu);
    }
}

// ---------------- Kernel B: merge 16 partial lists per column ----------------
__global__ __launch_bounds__(256) void topk_merge(
    const float* __restrict__ pv, const unsigned short* __restrict__ pi,
    float* __restrict__ outW,           // [B][T][NH]
    int*   __restrict__ outI)
{
    const int c   = blockIdx.x * 256 + threadIdx.x;  // [0, B*T)
    const int cg  = c >> 6;
    const int itl = c & 63;

    float cv[NH_]; int ci[NH_];
#pragma unroll
    for (int j = 0; j < NH_; ++j) { cv[j] = __int_as_float(0x7f800000); ci[j] = 0; }

    for (int sb = 0; sb < NSB; ++sb) {
        const size_t base = ((size_t)(cg * NSB + sb) * NH_) * 64 + itl;
        for (int j = 0; j < NH_; ++j) {
            float v = pv[base + (size_t)j * 64];
            if (!(v < cv[NH_ - 1])) break;       // ascending slices: stable ties
            int vi = (int)pi[base + (size_t)j * 64];
#pragma unroll
            for (int k = 0; k < NH_; ++k) {
                bool sw = v < cv[k];
                float tv = cv[k]; int ti = ci[k];
                cv[k] = sw ? v : tv;  ci[k] = sw ? vi : ti;
                v = sw ? tv : v;      vi = sw ? ti : vi;
            }
        }
    }

    const size_t base = (size_t)c * NH_;
#pragma unroll
    for (int j = 0; j < NH_; ++j) {
        float d = sqrtf(cv[j]) + 1e-15f;
        outW[base + j] = 1.0f / (d * d);
        outI[base + j] = ci[j];
    }
}

// ---------------- Kernel C: denom[b][nh] = sum_t w ----------------
__global__ __launch_bounds__(256) void denom_kernel(
    const float* __restrict__ outW, float* __restrict__ denom)
{
    const int ib = blockIdx.x >> 4;
    const int ih = blockIdx.x & 15;
    __shared__ float red[256];
    float acc = 0.f;
    for (int it = threadIdx.x; it < T_; it += 256)
        acc += outW[((size_t)ib * T_ + it) * NH_ + ih];
    red[threadIdx.x] = acc;
    __syncthreads();
    for (int s = 128; s > 0; s >>= 1) {
        if (threadIdx.x < s) red[threadIdx.x] += red[threadIdx.x + s];
        __syncthreads();
    }
    if (threadIdx.x == 0) denom[blockIdx.x] = red[0];
}

// ---------------- Kernel D: final gather + weighted sum ----------------
__global__ __launch_bounds__(256) void out_kernel(
    const float* __restrict__ x,        // [B][S]
    const float* __restrict__ outW,
    const int*   __restrict__ outI,
    const float* __restrict__ denom,    // [B][NH]
    float* __restrict__ out)            // [B][T]
{
    const int gid = blockIdx.x * 256 + threadIdx.x;
    const int i = gid >> 12;
    const int j = gid & 4095;
    const int ih = j >> 8;
    const size_t base = ((size_t)i * T_ + (size_t)(j & 255) * NH_) * NH_ + ih;
    const int dq = (j & 3) * NH_;
    float acc = 0.f;
#pragma unroll
    for (int k = 0; k < NH_; ++k) {
        float w  = outW[base + (size_t)k * NH_];
        int   id = outI[base + (size_t)k * NH_];
        acc += x[i * S_ + id] * w / denom[dq + k];
    }
    out[gid] = acc;
}

extern "C" void kernel_launch(void* const* d_in, const int* in_sizes, int n_in,
                              void* d_out, int out_size, void* d_ws, size_t ws_size,
                              hipStream_t stream) {
    const float* x      = (const float*)d_in[0];
    const float* coords = (const float*)d_in[1];
    float* out = (float*)d_out;

    const int nwaves = B_ * (T_ / 64) * NSB;                  // 4096 partial lists
    float*          pv    = (float*)d_ws;                                          // 16 MB
    unsigned short* pi    = (unsigned short*)(pv + (size_t)nwaves * NH_ * 64);     // 8 MB
    float*          outW  = (float*)(pi + (size_t)nwaves * NH_ * 64);              // 1 MB
    int*            outI  = (int*)(outW + (size_t)B_ * T_ * NH_);                  // 1 MB
    float*          denom = (float*)(outI + (size_t)B_ * T_ * NH_);                // 64 f32

    topk_scan   <<<B_ * (T_/64) * NSB / 4, 256, 0, stream>>>(coords, pv, pi);
    topk_merge  <<<B_ * T_ / 256,          256, 0, stream>>>(pv, pi, outW, outI);
    denom_kernel<<<B_ * NH_,               256, 0, stream>>>(outW, denom);
    out_kernel  <<<B_ * T_ / 256,          256, 0, stream>>>(x, outW, outI, denom, out);
}